// Round 7
// baseline (1233.359 us; speedup 1.0000x reference)
//
#include <hip/hip_runtime.h>
#include <hip/hip_bf16.h>

#define L_ 4
#define E_ 4
#define D_ 512
#define DFF_ 2048
#define H_ 8
#define B_ 16
#define T_ 256
#define S_ 512
#define HD_ 64
#define NSLOT 32   // B * K

typedef __attribute__((ext_vector_type(4))) float f32x4;
typedef __attribute__((ext_vector_type(8))) short bf16x8;
typedef __attribute__((ext_vector_type(4))) int i32x4;

static __device__ __forceinline__ float bf2f(unsigned short u){
  union{float f; unsigned u;} c; c.u = ((unsigned)u)<<16; return c.f;
}
static __device__ __forceinline__ unsigned short f2bf(float f){
  union{float f; unsigned u;} c; c.f=f;
  unsigned u=c.u;
  return (unsigned short)((u + 0x7FFFu + ((u>>16)&1u))>>16);
}

static __device__ __forceinline__ void gload16(const unsigned short* g, unsigned short* l){
  __builtin_amdgcn_global_load_lds(
      (const __attribute__((address_space(1))) void*)g,
      (__attribute__((address_space(3))) void*)l, 16, 0, 0);
}

// ---------------- routing ----------------
__global__ void __launch_bounds__(256) route_k(const float* __restrict__ x,
    const float* __restrict__ rw, int* __restrict__ eidx, float* __restrict__ wgt)
{
  __shared__ float pooled[D_];
  __shared__ float logit[E_];
  int b = blockIdx.x, tid = threadIdx.x;
  for (int d = tid; d < D_; d += 256) {
    float s = 0.f;
    const float* xp = x + ((long)b*T_)*D_ + d;
    for (int t=0;t<T_;t++) s += xp[(long)t*D_];
    pooled[d] = s * (1.f/T_);
  }
  __syncthreads();
  int wave = tid>>6, lane = tid&63;
  {
    float s=0.f;
    const float* w = rw + (long)wave*D_;
    for (int d=lane; d<D_; d+=64) s += pooled[d]*w[d];
    #pragma unroll
    for (int o=32;o;o>>=1) s += __shfl_xor(s,o);
    if (lane==0) logit[wave] = s;
  }
  __syncthreads();
  if (tid==0){
    int i1=0; float v1=logit[0];
    for (int e=1;e<E_;e++) if (logit[e] > v1){ v1=logit[e]; i1=e; }
    int i2=-1; float v2=-3.4e38f;
    for (int e=0;e<E_;e++) if (e!=i1 && logit[e] > v2){ v2=logit[e]; i2=e; }
    float e2 = __expf(v2 - v1);
    float w1 = 1.f/(1.f+e2);
    eidx[2*b]=i1; eidx[2*b+1]=i2;
    wgt[2*b]=w1; wgt[2*b+1]=e2*w1;
  }
}

// ---------------- casts ----------------
__global__ void __launch_bounds__(256) cast_bf16_k(const float* __restrict__ in,
    unsigned short* __restrict__ out, long n){
  long i = ((long)blockIdx.x*blockDim.x + threadIdx.x)*4;
  long st = (long)gridDim.x*blockDim.x*4;
  for (; i<n; i+=st){
    float4 v = *(const float4*)(in+i);
    ushort4 o; o.x=f2bf(v.x); o.y=f2bf(v.y); o.z=f2bf(v.z); o.w=f2bf(v.w);
    *(ushort4*)(out+i) = o;
  }
}

// fused per-layer weight cast (6 segments)
__global__ void __launch_bounds__(256) cast_weights_k(
    const float* __restrict__ s0, const float* __restrict__ s1,
    const float* __restrict__ s2, const float* __restrict__ s3,
    const float* __restrict__ s4, const float* __restrict__ s5,
    unsigned short* __restrict__ d0, unsigned short* __restrict__ d1,
    unsigned short* __restrict__ d2, unsigned short* __restrict__ d3,
    unsigned short* __restrict__ d4, unsigned short* __restrict__ d5)
{
  const long N0=(long)E_*3*D_*D_, N1=(long)E_*D_*D_;
  const long N2=N0, N3=N1, N4=(long)E_*DFF_*D_, N5=N4;
  const long total = N0+N1+N2+N3+N4+N5;
  long i = ((long)blockIdx.x*256 + threadIdx.x)*4;
  long st = (long)gridDim.x*256*4;
  for (; i<total; i+=st){
    const float* s; unsigned short* d; long j = i;
    if (j < N0){ s=s0; d=d0; }
    else if ((j-=N0) < N1){ s=s1; d=d1; }
    else if ((j-=N1) < N2){ s=s2; d=d2; }
    else if ((j-=N2) < N3){ s=s3; d=d3; }
    else if ((j-=N3) < N4){ s=s4; d=d4; }
    else { j-=N4; s=s5; d=d5; }
    float4 v = *(const float4*)(s+j);
    ushort4 o; o.x=f2bf(v.x); o.y=f2bf(v.y); o.z=f2bf(v.z); o.w=f2bf(v.w);
    *(ushort4*)(d+j) = o;
  }
}

// ---------------- V transpose: [rows, 64-per-head strided] -> [slot][h][64][rows] ----------------
__global__ void __launch_bounds__(256) vtrans_k(const unsigned short* __restrict__ src,
    long sSlot, int ld, unsigned short* __restrict__ dst, int rows)
{
  __shared__ unsigned short t[64][68];
  int s0 = blockIdx.x*64; int h = blockIdx.y; int slot = blockIdx.z;
  const unsigned short* sp = src + (long)slot*sSlot + (long)h*64;
  int c = threadIdx.x&63, w = threadIdx.x>>6;
  #pragma unroll
  for (int i=0;i<16;i++){
    int r = i*4 + w;
    t[r][c] = sp[(long)(s0+r)*ld + c];
  }
  __syncthreads();
  unsigned short* dp = dst + ((long)slot*H_ + h)*((long)64*rows) + s0;
  #pragma unroll
  for (int i=0;i<16;i++){
    int d = i*4 + w;
    dp[(long)d*rows + c] = t[c][d];
  }
}

// ---------------- fused flash attention (async-stage split, setprio on MFMA) ----------------
template<int NT>   // K tiles of 64: 4 (self) or 8 (cross)
__global__ void __launch_bounds__(256) fattn_k(
    const unsigned short* __restrict__ Qg, long qSlot, int ldq,
    const unsigned short* __restrict__ Kg, long kSlot, int ldk,
    const unsigned short* __restrict__ Vtg,
    unsigned short* __restrict__ Og, long oSlot, int ldo)
{
  constexpr int SLEN = NT*64;
  __shared__ unsigned short K_lds[64][72];
  __shared__ unsigned short V_lds[64][72];
  __shared__ unsigned short P_lds[4][16][72];

  int qb = blockIdx.x;
  int z  = blockIdx.y;            // slot*H + h
  int slot = z >> 3, h = z & 7;
  int tid = threadIdx.x, wave = tid>>6, lane = tid&63;
  int lr = lane&15, lg = lane>>4;
  int lk = lg*8;

  const unsigned short* Qp = Qg + (long)slot*qSlot + (long)h*HD_;
  const unsigned short* Kp = Kg + (long)slot*kSlot + (long)h*HD_;
  const unsigned short* Vp = Vtg + (long)z*((long)HD_*SLEN);

  bf16x8 qf[2];
  {
    int qrow = qb*64 + wave*16 + lr;
    const unsigned short* qr = Qp + (long)qrow*ldq;
    qf[0] = *(const bf16x8*)(qr + lk);
    qf[1] = *(const bf16x8*)(qr + 32 + lk);
  }

  float m_prev[4], l_run[4];
  f32x4 acc_o[4];
  #pragma unroll
  for (int r=0;r<4;r++){ m_prev[r]=-1e30f; l_run[r]=0.f; }
  #pragma unroll
  for (int ni=0;ni<4;ni++) acc_o[ni]=(f32x4){0.f,0.f,0.f,0.f};

  int srow = tid>>3, sch = tid&7;

  // prologue: load tile 0 into regs
  i32x4 kr0 = *(const i32x4*)(Kp + (long)srow*ldk + sch*8);
  i32x4 kr1 = *(const i32x4*)(Kp + (long)(srow+32)*ldk + sch*8);
  i32x4 vr0 = *(const i32x4*)(Vp + (long)srow*SLEN + sch*8);
  i32x4 vr1 = *(const i32x4*)(Vp + (long)(srow+32)*SLEN + sch*8);

  for (int t=0; t<NT; ++t){
    __syncthreads();   // all waves done reading prev tile's LDS
    *(i32x4*)&K_lds[srow][sch*8] = kr0;
    *(i32x4*)&K_lds[srow+32][sch*8] = kr1;
    *(i32x4*)&V_lds[srow][sch*8] = vr0;
    *(i32x4*)&V_lds[srow+32][sch*8] = vr1;
    __syncthreads();

    // issue next tile's loads NOW; they complete under the compute below
    int tn = (t+1 < NT) ? t+1 : t;
    int k0n = tn*64;
    kr0 = *(const i32x4*)(Kp + (long)(k0n+srow)*ldk + sch*8);
    kr1 = *(const i32x4*)(Kp + (long)(k0n+srow+32)*ldk + sch*8);
    vr0 = *(const i32x4*)(Vp + (long)srow*SLEN + k0n + sch*8);
    vr1 = *(const i32x4*)(Vp + (long)(srow+32)*SLEN + k0n + sch*8);

    // S = Q @ K^T
    f32x4 s[4];
    #pragma unroll
    for (int ni=0;ni<4;ni++) s[ni]=(f32x4){0.f,0.f,0.f,0.f};
    __builtin_amdgcn_s_setprio(1);
    #pragma unroll
    for (int ki=0;ki<2;ki++){
      #pragma unroll
      for (int ni=0;ni<4;ni++){
        bf16x8 kf = *(const bf16x8*)&K_lds[ni*16+lr][ki*32+lk];
        s[ni] = __builtin_amdgcn_mfma_f32_16x16x32_bf16(qf[ki], kf, s[ni],0,0,0);
      }
    }
    __builtin_amdgcn_s_setprio(0);
    // online softmax
    float tmax[4], corr[4], mnew[4];
    #pragma unroll
    for (int r=0;r<4;r++){
      tmax[r] = fmaxf(fmaxf(s[0][r],s[1][r]),fmaxf(s[2][r],s[3][r]));
      #pragma unroll
      for (int msk=1; msk<16; msk<<=1) tmax[r]=fmaxf(tmax[r], __shfl_xor(tmax[r],msk));
      mnew[r] = fmaxf(m_prev[r], tmax[r]);
      corr[r] = __expf(m_prev[r]-mnew[r]);
      m_prev[r] = mnew[r];
    }
    float rs[4] = {0.f,0.f,0.f,0.f};
    #pragma unroll
    for (int ni=0;ni<4;ni++){
      #pragma unroll
      for (int r=0;r<4;r++){
        float p = __expf(s[ni][r]-mnew[r]);
        rs[r] += p;
        P_lds[wave][lg*4+r][ni*16+lr] = f2bf(p);
      }
    }
    #pragma unroll
    for (int r=0;r<4;r++){
      #pragma unroll
      for (int msk=1; msk<16; msk<<=1) rs[r] += __shfl_xor(rs[r],msk);
      l_run[r] = l_run[r]*corr[r] + rs[r];
      #pragma unroll
      for (int ni=0;ni<4;ni++) acc_o[ni][r] *= corr[r];
    }
    // O += P @ V   (P_lds is wave-private: no barrier needed, lgkmcnt suffices)
    __builtin_amdgcn_s_setprio(1);
    #pragma unroll
    for (int ki=0;ki<2;ki++){
      bf16x8 pf = *(const bf16x8*)&P_lds[wave][lr][ki*32+lk];
      #pragma unroll
      for (int ni=0;ni<4;ni++){
        bf16x8 vf = *(const bf16x8*)&V_lds[ni*16+lr][ki*32+lk];
        acc_o[ni] = __builtin_amdgcn_mfma_f32_16x16x32_bf16(pf, vf, acc_o[ni],0,0,0);
      }
    }
    __builtin_amdgcn_s_setprio(0);
  }
  unsigned short* Op = Og + (long)slot*oSlot + (long)h*HD_;
  #pragma unroll
  for (int r=0;r<4;r++){
    float inv = 1.f/l_run[r];
    int q = qb*64 + wave*16 + lg*4 + r;
    #pragma unroll
    for (int ni=0;ni<4;ni++)
      Op[(long)q*ldo + ni*16 + lr] = f2bf(acc_o[ni][r]*inv);
  }
}

// ---------------- LDS-staged GEMM  C = A @ W^T (+bias)(*scale)(relu) ----------------
// BK=64, dbuf LDS, chunk-XOR swizzle, 8 waves (512 thr).
//   <128,128,64,32> : big GEMMs (round-5 proven, 64KB LDS, 2 blocks/CU)
//   <128, 64,32,32> : small GEMMs (49KB LDS, doubles grid -> 2 blocks/CU)
template<int BM, int BN, int WTM, int WTN>
__global__ void __launch_bounds__(512) gemm_lds(
    const unsigned short* __restrict__ A, long aSlot, int aDiv, long aHead, int lda,
    const unsigned short* __restrict__ W, long wSlot, long wHead, long wExp, int ldw,
    const int* __restrict__ eidx, const float* __restrict__ bias, long biasExp,
    void* __restrict__ Cp, long cSlot, long cHead, int ldc,
    int K, int HZ, int f32out, int relu, int scaleNlim, float scaleVal)
{
  constexpr int BK = 64;
  constexpr int WAVES_N = BN/WTN;
  constexpr int MI = WTM/16, NI = WTN/16;
  static_assert((BM/WTM)*(BN/WTN) == 8, "8 waves");
  static_assert((BM*8)%512==0 && (BN*8)%512==0, "stage coverage");
  __shared__ unsigned short smem[2*(BM+BN)*BK];

  int z = blockIdx.z;
  int slot = z / HZ;
  int h = z - slot*HZ;
  int e = eidx ? eidx[slot] : 0;
  const unsigned short* Ap = A + (long)(slot/aDiv)*aSlot + (long)h*aHead;
  const unsigned short* Wp = W + (long)slot*wSlot + (long)h*wHead + (long)e*wExp;
  const float* bp = bias ? (bias + (long)e*biasExp) : nullptr;

  int tid  = threadIdx.x;
  int wave = tid>>6, lane = tid&63;
  int wm = wave / WAVES_N, wn = wave % WAVES_N;
  int bm0 = blockIdx.y*BM;
  int bn0 = blockIdx.x*BN;
  int lr = lane&15;
  int lg = lane>>4;
  int r7 = lr&7;

  Ap += (long)bm0*lda;
  Wp += (long)bn0*ldw;

  f32x4 acc[MI][NI];
  #pragma unroll
  for (int i=0;i<MI;i++)
  #pragma unroll
  for (int j=0;j<NI;j++) acc[i][j] = (f32x4){0.f,0.f,0.f,0.f};

  // staging: chunk -> LDS linear; global src chunk = (c ^ (row&7))
  auto stage = [&](int buf, int k0){
    unsigned short* as = &smem[(size_t)buf*(BM+BN)*BK];
    unsigned short* bs = as + BM*BK;
    #pragma unroll
    for (int i=0;i<BM*8/512;i++){
      int cch = i*512 + tid;
      int row = cch >> 3, c = cch & 7;
      gload16(Ap + (long)row*lda + k0 + ((c ^ (row&7))<<3), as + cch*8);
    }
    #pragma unroll
    for (int i=0;i<BN*8/512;i++){
      int cch = i*512 + tid;
      int row = cch >> 3, c = cch & 7;
      gload16(Wp + (long)row*ldw + k0 + ((c ^ (row&7))<<3), bs + cch*8);
    }
  };

  auto compute = [&](int buf){
    unsigned short* as = &smem[(size_t)buf*(BM+BN)*BK];
    unsigned short* bs = as + BM*BK;
    #pragma unroll
    for (int ki=0;ki<2;ki++){
      bf16x8 af[MI], bfr[NI];
      #pragma unroll
      for (int mi=0;mi<MI;mi++){
        int row = wm*WTM + mi*16 + lr;
        af[mi] = *(const bf16x8*)&as[row*BK + (((ki*4+lg) ^ r7)<<3)];
      }
      #pragma unroll
      for (int ni=0;ni<NI;ni++){
        int row = wn*WTN + ni*16 + lr;
        bfr[ni] = *(const bf16x8*)&bs[row*BK + (((ki*4+lg) ^ r7)<<3)];
      }
      #pragma unroll
      for (int mi=0;mi<MI;mi++)
      #pragma unroll
      for (int ni=0;ni<NI;ni++)
        acc[mi][ni] = __builtin_amdgcn_mfma_f32_16x16x32_bf16(af[mi], bfr[ni], acc[mi][ni], 0,0,0);
    }
  };

  int NT = K / BK;
  stage(0, 0);
  __syncthreads();
  int cur = 0;
  for (int t=0; t<NT; ++t){
    if (t+1 < NT) stage(cur^1, (t+1)*BK);
    compute(cur);
    __syncthreads();
    cur ^= 1;
  }

  long cbase = (long)slot*cSlot + (long)h*cHead;
  int rbase = lg*4;
  #pragma unroll
  for (int mi=0;mi<MI;mi++)
  #pragma unroll
  for (int ni=0;ni<NI;ni++){
    f32x4 v = acc[mi][ni];
    int n = bn0 + wn*WTN + ni*16 + lr;
    float bv = bp ? bp[n] : 0.f;
    float scv = (n < scaleNlim) ? scaleVal : 1.f;
    #pragma unroll
    for (int r=0;r<4;r++){
      int m = bm0 + wm*WTM + mi*16 + rbase + r;
      float val = (v[r] + bv) * scv;
      if (relu) val = fmaxf(val, 0.f);
      long o = cbase + (long)m*ldc + n;
      if (f32out) ((float*)Cp)[o] = val;
      else ((unsigned short*)Cp)[o] = f2bf(val);
    }
  }
}

// ---------------- residual add + LayerNorm (per-slot out) ----------------
__global__ void __launch_bounds__(256) add_ln_k(
    const float* __restrict__ Ab, int aDiv, long aStride,
    const float* __restrict__ Bb, long bStride,
    const float* __restrict__ G, const float* __restrict__ Bt,
    const int* __restrict__ eidx,
    float* __restrict__ OutF, unsigned short* __restrict__ OutB)
{
  int row = blockIdx.x*4 + (threadIdx.x>>6);
  int slot = row>>8, t = row&255;
  int lane = threadIdx.x&63;
  const float* a = Ab + (long)(slot/aDiv)*aStride + (long)t*D_;
  const float* b = Bb + (long)slot*bStride + (long)t*D_;
  int e = eidx[slot];
  const float* g  = G  + (long)e*D_;
  const float* bt = Bt + (long)e*D_;
  float x[8]; float s=0.f;
  #pragma unroll
  for (int i=0;i<8;i++){ x[i] = a[lane+i*64]+b[lane+i*64]; s+=x[i]; }
  #pragma unroll
  for (int o=32;o;o>>=1) s += __shfl_xor(s,o);
  float m = s*(1.f/D_);
  float q=0.f;
  #pragma unroll
  for (int i=0;i<8;i++){ float d=x[i]-m; q+=d*d; }
  #pragma unroll
  for (int o=32;o;o>>=1) q += __shfl_xor(q,o);
  float rs = rsqrtf(q*(1.f/D_)+1e-5f);
  long ob = (long)slot*(T_*D_) + (long)t*D_;
  #pragma unroll
  for (int i=0;i<8;i++){
    int d = lane+i*64;
    float y = (x[i]-m)*rs*g[d]+bt[d];
    OutF[ob+d]=y;
    if (OutB) OutB[ob+d]=f2bf(y);
  }
}

// ---------------- residual add + LayerNorm (n3) + weighted slot combine ----------------
__global__ void __launch_bounds__(256) add_ln_comb_k(
    const float* __restrict__ x2, const float* __restrict__ proj,
    const float* __restrict__ G, const float* __restrict__ Bt,
    const int* __restrict__ eidx, const float* __restrict__ wgt,
    float* __restrict__ dstF, unsigned short* __restrict__ dstB)
{
  int row = blockIdx.x*4 + (threadIdx.x>>6);   // 0..B*T-1 : b*256+t
  int b = row>>8, t = row&255;
  int lane = threadIdx.x&63;
  float out[8];
  #pragma unroll
  for (int i=0;i<8;i++) out[i]=0.f;
  #pragma unroll
  for (int s2i=0;s2i<2;s2i++){
    int slot = 2*b + s2i;
    int e = eidx[slot];
    float w = wgt[slot];
    const float* a = x2 + (long)slot*(T_*D_) + (long)t*D_;
    const float* p = proj + (long)slot*(T_*D_) + (long)t*D_;
    const float* g  = G  + (long)e*D_;
    const float* bt = Bt + (long)e*D_;
    float x[8]; float s=0.f;
    #pragma unroll
    for (int i=0;i<8;i++){ x[i] = a[lane+i*64]+p[lane+i*64]; s+=x[i]; }
    #pragma unroll
    for (int o=32;o;o>>=1) s += __shfl_xor(s,o);
    float m = s*(1.f/D_);
    float q=0.f;
    #pragma unroll
    for (int i=0;i<8;i++){ float d=x[i]-m; q+=d*d; }
    #pragma unroll
    for (int o=32;o;o>>=1) q += __shfl_xor(q,o);
    float rs = rsqrtf(q*(1.f/D_)+1e-5f);
    #pragma unroll
    for (int i=0;i<8;i++){
      int d = lane+i*64;
      out[i] += w*((x[i]-m)*rs*g[d]+bt[d]);
    }
  }
  long ob = (long)row*D_;
  #pragma unroll
  for (int i=0;i<8;i++){
    int d = lane+i*64;
    dstF[ob+d] = out[i];
    dstB[ob+d] = f2bf(out[i]);
  }
}

extern "C" void kernel_launch(void* const* d_in, const int* in_sizes, int n_in,
                              void* d_out, int out_size, void* d_ws, size_t ws_size,
                              hipStream_t stream)
{
  const float* tgt      = (const float*)d_in[0];
  const float* memory   = (const float*)d_in[1];
  const float* router_w = (const float*)d_in[2];
  const float* sa_in_w  = (const float*)d_in[3];
  const float* sa_in_b  = (const float*)d_in[4];
  const float* sa_out_w = (const float*)d_in[5];
  const float* sa_out_b = (const float*)d_in[6];
  const float* ca_in_w  = (const float*)d_in[7];
  const float* ca_in_b  = (const float*)d_in[8];
  const float* ca_out_w = (const float*)d_in[9];
  const float* ca_out_b = (const float*)d_in[10];
  const float* lin1_w   = (const float*)d_in[11];
  const float* lin1_b   = (const float*)d_in[12];
  const float* lin2_w   = (const float*)d_in[13];
  const float* lin2_b   = (const float*)d_in[14];
  const float* n1_g = (const float*)d_in[15];
  const float* n1_b = (const float*)d_in[16];
  const float* n2_g = (const float*)d_in[17];
  const float* n2_b = (const float*)d_in[18];
  const float* n3_g = (const float*)d_in[19];
  const float* n3_b = (const float*)d_in[20];

  char* ws = (char*)d_ws;
  size_t off = 0;
  auto alloc = [&](size_t bytes)->char*{
    char* p = ws + off; off += (bytes + 255) & ~(size_t)255; return p;
  };
  unsigned short* xb    = (unsigned short*)alloc(2ull*B_*T_*D_);
  unsigned short* memb  = (unsigned short*)alloc(2ull*B_*S_*D_);
  float*          x     = (float*)alloc(4ull*B_*T_*D_);
  int*            eidx  = (int*)alloc(4ull*NSLOT);
  float*          wgt   = (float*)alloc(4ull*NSLOT);
  unsigned short* wSaIn  = (unsigned short*)alloc(2ull*E_*3*D_*D_);
  unsigned short* wSaOut = (unsigned short*)alloc(2ull*E_*D_*D_);
  unsigned short* wCaIn  = (unsigned short*)alloc(2ull*E_*3*D_*D_);
  unsigned short* wCaOut = (unsigned short*)alloc(2ull*E_*D_*D_);
  unsigned short* wL1    = (unsigned short*)alloc(2ull*E_*DFF_*D_);
  unsigned short* wL2    = (unsigned short*)alloc(2ull*E_*D_*DFF_);
  unsigned short* qkv   = (unsigned short*)alloc(2ull*NSLOT*T_*3*D_);
  unsigned short* ffh   = (unsigned short*)alloc(2ull*NSLOT*T_*DFF_);
  unsigned short* attn  = (unsigned short*)alloc(2ull*NSLOT*T_*D_);
  float*          proj  = (float*)alloc(4ull*NSLOT*T_*D_);
  float*          x1    = (float*)alloc(4ull*NSLOT*T_*D_);
  unsigned short* x1b   = (unsigned short*)alloc(2ull*NSLOT*T_*D_);
  unsigned short* cq    = (unsigned short*)alloc(2ull*NSLOT*T_*D_);
  unsigned short* mkv   = (unsigned short*)alloc(2ull*NSLOT*S_*2*D_);
  float*          x2    = (float*)alloc(4ull*NSLOT*T_*D_);
  unsigned short* x2b   = (unsigned short*)alloc(2ull*NSLOT*T_*D_);
  unsigned short* Vt1   = cq;   // alias: [slot][h][64][T]; cq written after fattn-self consumed Vt1
  unsigned short* Vt2   = qkv;  // alias: [slot][h][64][S]; qkv dead after fattn-self

  cast_bf16_k<<<1024,256,0,stream>>>(tgt,    xb,   (long)B_*T_*D_);
  cast_bf16_k<<<1024,256,0,stream>>>(memory, memb, (long)B_*S_*D_);

  const float* xcur = tgt;
  for (int l=0; l<L_; ++l){
    route_k<<<B_,256,0,stream>>>(xcur, router_w + (size_t)l*E_*D_, eidx, wgt);
    cast_weights_k<<<2048,256,0,stream>>>(
      sa_in_w  + (size_t)l*E_*3*D_*D_, sa_out_w + (size_t)l*E_*D_*D_,
      ca_in_w  + (size_t)l*E_*3*D_*D_, ca_out_w + (size_t)l*E_*D_*D_,
      lin1_w   + (size_t)l*E_*DFF_*D_, lin2_w   + (size_t)l*E_*D_*DFF_,
      wSaIn, wSaOut, wCaIn, wCaOut, wL1, wL2);

    // QKV = x @ sa_in^T + b  (Q cols scaled by 1/8)
    gemm_lds<128,128,64,32><<<dim3(12,2,NSLOT),512,0,stream>>>(
      xb, (long)T_*D_, 2, 0, D_,
      wSaIn, 0, 0, (long)3*D_*D_, D_,
      eidx, sa_in_b + (size_t)l*E_*3*D_, 3*D_,
      qkv, (long)T_*3*D_, 0, 3*D_,
      512, 1, 0, 0, D_, 0.125f);
    // Vt1 = transpose of self V
    vtrans_k<<<dim3(T_/64,H_,NSLOT),256,0,stream>>>(
      qkv + 2*D_, (long)T_*3*D_, 3*D_, Vt1, T_);
    // fused self-attention
    fattn_k<4><<<dim3(T_/64, NSLOT*H_),256,0,stream>>>(
      qkv, (long)T_*3*D_, 3*D_,
      qkv + D_, (long)T_*3*D_, 3*D_,
      Vt1, attn, (long)T_*D_, D_);
    // self-attn out proj (fp32 out)
    gemm_lds<128,64,32,32><<<dim3(8,2,NSLOT),512,0,stream>>>(
      attn, (long)T_*D_, 1, 0, D_,
      wSaOut, 0, 0, (long)D_*D_, D_,
      eidx, sa_out_b + (size_t)l*E_*D_, D_,
      proj, (long)T_*D_, 0, D_,
      512, 1, 1, 0, 0, 1.f);
    add_ln_k<<<2048,256,0,stream>>>(xcur, 2, (long)T_*D_, proj, (long)T_*D_,
      n1_g + (size_t)l*E_*D_, n1_b + (size_t)l*E_*D_, eidx, x1, x1b);
    // cross-attn Q (scaled)
    gemm_lds<128,64,32,32><<<dim3(8,2,NSLOT),512,0,stream>>>(
      x1b, (long)T_*D_, 1, 0, D_,
      wCaIn, 0, 0, (long)3*D_*D_, D_,
      eidx, ca_in_b + (size_t)l*E_*3*D_, 3*D_,
      cq, (long)T_*D_, 0, D_,
      512, 1, 0, 0, D_, 0.125f);
    // cross-attn K,V from memory
    gemm_lds<128,128,64,32><<<dim3(8,4,NSLOT),512,0,stream>>>(
      memb, (long)S_*D_, 2, 0, D_,
      wCaIn + (size_t)D_*D_, 0, 0, (long)3*D_*D_, D_,
      eidx, ca_in_b + (size_t)l*E_*3*D_ + D_, 3*D_,
      mkv, (long)S_*2*D_, 0, 2*D_,
      512, 1, 0, 0, 0, 1.f);
    // Vt2 = transpose of cross V
    vtrans_k<<<dim3(S_/64,H_,NSLOT),256,0,stream>>>(
      mkv + D_, (long)S_*2*D_, 2*D_, Vt2, S_);
    // fused cross-attention
    fattn_k<8><<<dim3(T_/64, NSLOT*H_),256,0,stream>>>(
      cq, (long)T_*D_, D_,
      mkv, (long)S_*2*D_, 2*D_,
      Vt2, attn, (long)T_*D_, D_);
    // cross-attn out proj (fp32 out)
    gemm_lds<128,64,32,32><<<dim3(8,2,NSLOT),512,0,stream>>>(
      attn, (long)T_*D_, 1, 0, D_,
      wCaOut, 0, 0, (long)D_*D_, D_,
      eidx, ca_out_b + (size_t)l*E_*D_, D_,
      proj, (long)T_*D_, 0, D_,
      512, 1, 1, 0, 0, 1.f);
    add_ln_k<<<2048,256,0,stream>>>(x1, 1, (long)T_*D_, proj, (long)T_*D_,
      n2_g + (size_t)l*E_*D_, n2_b + (size_t)l*E_*D_, eidx, x2, x2b);
    // FFN1 (+relu)
    gemm_lds<128,128,64,32><<<dim3(16,2,NSLOT),512,0,stream>>>(
      x2b, (long)T_*D_, 1, 0, D_,
      wL1, 0, 0, (long)DFF_*D_, D_,
      eidx, lin1_b + (size_t)l*E_*DFF_, DFF_,
      ffh, (long)T_*DFF_, 0, DFF_,
      512, 1, 0, 1, 0, 1.f);
    // FFN2 (fp32 out)
    gemm_lds<128,64,32,32><<<dim3(8,2,NSLOT),512,0,stream>>>(
      ffh, (long)T_*DFF_, 1, 0, DFF_,
      wL2, 0, 0, (long)D_*DFF_, DFF_,
      eidx, lin2_b + (size_t)l*E_*D_, D_,
      proj, (long)T_*D_, 0, D_,
      2048, 1, 1, 0, 0, 1.f);
    // n3 LN + weighted combine of the two slots (writes next x / xb, or d_out)
    float* dstF = (l==L_-1) ? (float*)d_out : x;
    add_ln_comb_k<<<1024,256,0,stream>>>(x2, proj,
      n3_g + (size_t)l*E_*D_, n3_b + (size_t)l*E_*D_, eidx, wgt, dstF, xb);
    xcur = x;
  }
}

// Round 8
// 1140.640 us; speedup vs baseline: 1.0813x; 1.0813x over previous
//
#include <hip/hip_runtime.h>
#include <hip/hip_bf16.h>

#define L_ 4
#define E_ 4
#define D_ 512
#define DFF_ 2048
#define H_ 8
#define B_ 16
#define T_ 256
#define S_ 512
#define HD_ 64
#define NSLOT 32   // B * K

typedef __attribute__((ext_vector_type(4))) float f32x4;
typedef __attribute__((ext_vector_type(8))) short bf16x8;
typedef __attribute__((ext_vector_type(4))) int i32x4;

static __device__ __forceinline__ float bf2f(unsigned short u){
  union{float f; unsigned u;} c; c.u = ((unsigned)u)<<16; return c.f;
}
static __device__ __forceinline__ unsigned short f2bf(float f){
  union{float f; unsigned u;} c; c.f=f;
  unsigned u=c.u;
  return (unsigned short)((u + 0x7FFFu + ((u>>16)&1u))>>16);
}

static __device__ __forceinline__ void gload16(const unsigned short* g, unsigned short* l){
  __builtin_amdgcn_global_load_lds(
      (const __attribute__((address_space(1))) void*)g,
      (__attribute__((address_space(3))) void*)l, 16, 0, 0);
}

// ---------------- routing ----------------
__global__ void __launch_bounds__(256) route_k(const float* __restrict__ x,
    const float* __restrict__ rw, int* __restrict__ eidx, float* __restrict__ wgt)
{
  __shared__ float pooled[D_];
  __shared__ float logit[E_];
  int b = blockIdx.x, tid = threadIdx.x;
  for (int d = tid; d < D_; d += 256) {
    float s = 0.f;
    const float* xp = x + ((long)b*T_)*D_ + d;
    for (int t=0;t<T_;t++) s += xp[(long)t*D_];
    pooled[d] = s * (1.f/T_);
  }
  __syncthreads();
  int wave = tid>>6, lane = tid&63;
  {
    float s=0.f;
    const float* w = rw + (long)wave*D_;
    for (int d=lane; d<D_; d+=64) s += pooled[d]*w[d];
    #pragma unroll
    for (int o=32;o;o>>=1) s += __shfl_xor(s,o);
    if (lane==0) logit[wave] = s;
  }
  __syncthreads();
  if (tid==0){
    int i1=0; float v1=logit[0];
    for (int e=1;e<E_;e++) if (logit[e] > v1){ v1=logit[e]; i1=e; }
    int i2=-1; float v2=-3.4e38f;
    for (int e=0;e<E_;e++) if (e!=i1 && logit[e] > v2){ v2=logit[e]; i2=e; }
    float e2 = __expf(v2 - v1);
    float w1 = 1.f/(1.f+e2);
    eidx[2*b]=i1; eidx[2*b+1]=i2;
    wgt[2*b]=w1; wgt[2*b+1]=e2*w1;
  }
}

// ---------------- casts ----------------
__global__ void __launch_bounds__(256) cast_bf16_k(const float* __restrict__ in,
    unsigned short* __restrict__ out, long n){
  long i = ((long)blockIdx.x*blockDim.x + threadIdx.x)*4;
  long st = (long)gridDim.x*blockDim.x*4;
  for (; i<n; i+=st){
    float4 v = *(const float4*)(in+i);
    ushort4 o; o.x=f2bf(v.x); o.y=f2bf(v.y); o.z=f2bf(v.z); o.w=f2bf(v.w);
    *(ushort4*)(out+i) = o;
  }
}

// fused per-layer weight cast (6 segments)
__global__ void __launch_bounds__(256) cast_weights_k(
    const float* __restrict__ s0, const float* __restrict__ s1,
    const float* __restrict__ s2, const float* __restrict__ s3,
    const float* __restrict__ s4, const float* __restrict__ s5,
    unsigned short* __restrict__ d0, unsigned short* __restrict__ d1,
    unsigned short* __restrict__ d2, unsigned short* __restrict__ d3,
    unsigned short* __restrict__ d4, unsigned short* __restrict__ d5)
{
  const long N0=(long)E_*3*D_*D_, N1=(long)E_*D_*D_;
  const long N2=N0, N3=N1, N4=(long)E_*DFF_*D_, N5=N4;
  const long total = N0+N1+N2+N3+N4+N5;
  long i = ((long)blockIdx.x*256 + threadIdx.x)*4;
  long st = (long)gridDim.x*256*4;
  for (; i<total; i+=st){
    const float* s; unsigned short* d; long j = i;
    if (j < N0){ s=s0; d=d0; }
    else if ((j-=N0) < N1){ s=s1; d=d1; }
    else if ((j-=N1) < N2){ s=s2; d=d2; }
    else if ((j-=N2) < N3){ s=s3; d=d3; }
    else if ((j-=N3) < N4){ s=s4; d=d4; }
    else { j-=N4; s=s5; d=d5; }
    float4 v = *(const float4*)(s+j);
    ushort4 o; o.x=f2bf(v.x); o.y=f2bf(v.y); o.z=f2bf(v.z); o.w=f2bf(v.w);
    *(ushort4*)(d+j) = o;
  }
}

// ---------------- V transpose: [rows, 64-per-head strided] -> [slot][h][64][rows] ----------------
__global__ void __launch_bounds__(256) vtrans_k(const unsigned short* __restrict__ src,
    long sSlot, int ld, unsigned short* __restrict__ dst, int rows)
{
  __shared__ unsigned short t[64][68];
  int s0 = blockIdx.x*64; int h = blockIdx.y; int slot = blockIdx.z;
  const unsigned short* sp = src + (long)slot*sSlot + (long)h*64;
  int c = threadIdx.x&63, w = threadIdx.x>>6;
  #pragma unroll
  for (int i=0;i<16;i++){
    int r = i*4 + w;
    t[r][c] = sp[(long)(s0+r)*ld + c];
  }
  __syncthreads();
  unsigned short* dp = dst + ((long)slot*H_ + h)*((long)64*rows) + s0;
  #pragma unroll
  for (int i=0;i<16;i++){
    int d = i*4 + w;
    dp[(long)d*rows + c] = t[c][d];
  }
}

// ---------------- fused flash attention (async-stage split, setprio on MFMA) ----------------
template<int NT>   // K tiles of 64: 4 (self) or 8 (cross)
__global__ void __launch_bounds__(256) fattn_k(
    const unsigned short* __restrict__ Qg, long qSlot, int ldq,
    const unsigned short* __restrict__ Kg, long kSlot, int ldk,
    const unsigned short* __restrict__ Vtg,
    unsigned short* __restrict__ Og, long oSlot, int ldo)
{
  constexpr int SLEN = NT*64;
  __shared__ unsigned short K_lds[64][72];
  __shared__ unsigned short V_lds[64][72];
  __shared__ unsigned short P_lds[4][16][72];

  int qb = blockIdx.x;
  int z  = blockIdx.y;            // slot*H + h
  int slot = z >> 3, h = z & 7;
  int tid = threadIdx.x, wave = tid>>6, lane = tid&63;
  int lr = lane&15, lg = lane>>4;
  int lk = lg*8;

  const unsigned short* Qp = Qg + (long)slot*qSlot + (long)h*HD_;
  const unsigned short* Kp = Kg + (long)slot*kSlot + (long)h*HD_;
  const unsigned short* Vp = Vtg + (long)z*((long)HD_*SLEN);

  bf16x8 qf[2];
  {
    int qrow = qb*64 + wave*16 + lr;
    const unsigned short* qr = Qp + (long)qrow*ldq;
    qf[0] = *(const bf16x8*)(qr + lk);
    qf[1] = *(const bf16x8*)(qr + 32 + lk);
  }

  float m_prev[4], l_run[4];
  f32x4 acc_o[4];
  #pragma unroll
  for (int r=0;r<4;r++){ m_prev[r]=-1e30f; l_run[r]=0.f; }
  #pragma unroll
  for (int ni=0;ni<4;ni++) acc_o[ni]=(f32x4){0.f,0.f,0.f,0.f};

  int srow = tid>>3, sch = tid&7;

  // prologue: load tile 0 into regs
  i32x4 kr0 = *(const i32x4*)(Kp + (long)srow*ldk + sch*8);
  i32x4 kr1 = *(const i32x4*)(Kp + (long)(srow+32)*ldk + sch*8);
  i32x4 vr0 = *(const i32x4*)(Vp + (long)srow*SLEN + sch*8);
  i32x4 vr1 = *(const i32x4*)(Vp + (long)(srow+32)*SLEN + sch*8);

  for (int t=0; t<NT; ++t){
    __syncthreads();   // all waves done reading prev tile's LDS
    *(i32x4*)&K_lds[srow][sch*8] = kr0;
    *(i32x4*)&K_lds[srow+32][sch*8] = kr1;
    *(i32x4*)&V_lds[srow][sch*8] = vr0;
    *(i32x4*)&V_lds[srow+32][sch*8] = vr1;
    __syncthreads();

    // issue next tile's loads NOW; they complete under the compute below
    int tn = (t+1 < NT) ? t+1 : t;
    int k0n = tn*64;
    kr0 = *(const i32x4*)(Kp + (long)(k0n+srow)*ldk + sch*8);
    kr1 = *(const i32x4*)(Kp + (long)(k0n+srow+32)*ldk + sch*8);
    vr0 = *(const i32x4*)(Vp + (long)srow*SLEN + k0n + sch*8);
    vr1 = *(const i32x4*)(Vp + (long)(srow+32)*SLEN + k0n + sch*8);

    // S = Q @ K^T
    f32x4 s[4];
    #pragma unroll
    for (int ni=0;ni<4;ni++) s[ni]=(f32x4){0.f,0.f,0.f,0.f};
    __builtin_amdgcn_s_setprio(1);
    #pragma unroll
    for (int ki=0;ki<2;ki++){
      #pragma unroll
      for (int ni=0;ni<4;ni++){
        bf16x8 kf = *(const bf16x8*)&K_lds[ni*16+lr][ki*32+lk];
        s[ni] = __builtin_amdgcn_mfma_f32_16x16x32_bf16(qf[ki], kf, s[ni],0,0,0);
      }
    }
    __builtin_amdgcn_s_setprio(0);
    // online softmax
    float tmax[4], corr[4], mnew[4];
    #pragma unroll
    for (int r=0;r<4;r++){
      tmax[r] = fmaxf(fmaxf(s[0][r],s[1][r]),fmaxf(s[2][r],s[3][r]));
      #pragma unroll
      for (int msk=1; msk<16; msk<<=1) tmax[r]=fmaxf(tmax[r], __shfl_xor(tmax[r],msk));
      mnew[r] = fmaxf(m_prev[r], tmax[r]);
      corr[r] = __expf(m_prev[r]-mnew[r]);
      m_prev[r] = mnew[r];
    }
    float rs[4] = {0.f,0.f,0.f,0.f};
    #pragma unroll
    for (int ni=0;ni<4;ni++){
      #pragma unroll
      for (int r=0;r<4;r++){
        float p = __expf(s[ni][r]-mnew[r]);
        rs[r] += p;
        P_lds[wave][lg*4+r][ni*16+lr] = f2bf(p);
      }
    }
    #pragma unroll
    for (int r=0;r<4;r++){
      #pragma unroll
      for (int msk=1; msk<16; msk<<=1) rs[r] += __shfl_xor(rs[r],msk);
      l_run[r] = l_run[r]*corr[r] + rs[r];
      #pragma unroll
      for (int ni=0;ni<4;ni++) acc_o[ni][r] *= corr[r];
    }
    // O += P @ V   (P_lds is wave-private: no barrier needed, lgkmcnt suffices)
    __builtin_amdgcn_s_setprio(1);
    #pragma unroll
    for (int ki=0;ki<2;ki++){
      bf16x8 pf = *(const bf16x8*)&P_lds[wave][lr][ki*32+lk];
      #pragma unroll
      for (int ni=0;ni<4;ni++){
        bf16x8 vf = *(const bf16x8*)&V_lds[ni*16+lr][ki*32+lk];
        acc_o[ni] = __builtin_amdgcn_mfma_f32_16x16x32_bf16(pf, vf, acc_o[ni],0,0,0);
      }
    }
    __builtin_amdgcn_s_setprio(0);
  }
  unsigned short* Op = Og + (long)slot*oSlot + (long)h*HD_;
  #pragma unroll
  for (int r=0;r<4;r++){
    float inv = 1.f/l_run[r];
    int q = qb*64 + wave*16 + lg*4 + r;
    #pragma unroll
    for (int ni=0;ni<4;ni++)
      Op[(long)q*ldo + ni*16 + lr] = f2bf(acc_o[ni][r]*inv);
  }
}

// ---------------- LDS-staged GEMM  C = A @ W^T (+bias)(*scale)(relu) ----------------
// dbuf LDS, chunk-XOR swizzle, 8 waves (512 thr).
//   <128,128,64,32,64> : small GEMMs (r5-proven, 64KB LDS, 2 blocks/CU)
//   <128,256,64,64,32> : big GEMMs (49KB LDS, ~3 blocks/CU, 64x64 wave tile = 1.5x LDS F/B)
template<int BM, int BN, int WTM, int WTN, int BK>
__global__ void __launch_bounds__(512) gemm_lds(
    const unsigned short* __restrict__ A, long aSlot, int aDiv, long aHead, int lda,
    const unsigned short* __restrict__ W, long wSlot, long wHead, long wExp, int ldw,
    const int* __restrict__ eidx, const float* __restrict__ bias, long biasExp,
    void* __restrict__ Cp, long cSlot, long cHead, int ldc,
    int K, int HZ, int f32out, int relu, int scaleNlim, float scaleVal)
{
  constexpr int WAVES_N = BN/WTN;
  constexpr int MI = WTM/16, NI = WTN/16;
  constexpr int SLOTS = BK/8;            // 16B chunks per row
  static_assert((BM/WTM)*(BN/WTN) == 8, "8 waves");
  static_assert((BM*SLOTS)%512==0 && (BN*SLOTS)%512==0, "stage coverage");
  __shared__ unsigned short smem[2*(BM+BN)*BK];

  int z = blockIdx.z;
  int slot = z / HZ;
  int h = z - slot*HZ;
  int e = eidx ? eidx[slot] : 0;
  const unsigned short* Ap = A + (long)(slot/aDiv)*aSlot + (long)h*aHead;
  const unsigned short* Wp = W + (long)slot*wSlot + (long)h*wHead + (long)e*wExp;
  const float* bp = bias ? (bias + (long)e*biasExp) : nullptr;

  int tid  = threadIdx.x;
  int wave = tid>>6, lane = tid&63;
  int wm = wave / WAVES_N, wn = wave % WAVES_N;
  int bm0 = blockIdx.y*BM;
  int bn0 = blockIdx.x*BN;
  int lr = lane&15;
  int lg = lane>>4;
  // fragment k-slot swizzle term (uniform across fragments: frag row = base16 + lr)
  int swz = (BK==64) ? (lr&7) : ((lr>>1)&3);

  Ap += (long)bm0*lda;
  Wp += (long)bn0*ldw;

  f32x4 acc[MI][NI];
  #pragma unroll
  for (int i=0;i<MI;i++)
  #pragma unroll
  for (int j=0;j<NI;j++) acc[i][j] = (f32x4){0.f,0.f,0.f,0.f};

  // staging: chunk -> LDS linear; global src chunk index is XOR-permuted per row
  auto stage = [&](int buf, int k0){
    unsigned short* as = &smem[(size_t)buf*(BM+BN)*BK];
    unsigned short* bs = as + BM*BK;
    #pragma unroll
    for (int i=0;i<BM*SLOTS/512;i++){
      int cch = i*512 + tid;
      int row = cch / SLOTS, c = cch % SLOTS;
      int cs = (BK==64) ? (c ^ (row&7)) : (c ^ ((row>>1)&3));
      gload16(Ap + (long)row*lda + k0 + (cs<<3), as + cch*8);
    }
    #pragma unroll
    for (int i=0;i<BN*SLOTS/512;i++){
      int cch = i*512 + tid;
      int row = cch / SLOTS, c = cch % SLOTS;
      int cs = (BK==64) ? (c ^ (row&7)) : (c ^ ((row>>1)&3));
      gload16(Wp + (long)row*ldw + k0 + (cs<<3), bs + cch*8);
    }
  };

  auto compute = [&](int buf){
    unsigned short* as = &smem[(size_t)buf*(BM+BN)*BK];
    unsigned short* bs = as + BM*BK;
    #pragma unroll
    for (int ki=0;ki<BK/32;ki++){
      bf16x8 af[MI], bfr[NI];
      #pragma unroll
      for (int mi=0;mi<MI;mi++){
        int row = wm*WTM + mi*16 + lr;
        af[mi] = *(const bf16x8*)&as[row*BK + (((ki*4+lg) ^ swz)<<3)];
      }
      #pragma unroll
      for (int ni=0;ni<NI;ni++){
        int row = wn*WTN + ni*16 + lr;
        bfr[ni] = *(const bf16x8*)&bs[row*BK + (((ki*4+lg) ^ swz)<<3)];
      }
      __builtin_amdgcn_s_setprio(1);
      #pragma unroll
      for (int mi=0;mi<MI;mi++)
      #pragma unroll
      for (int ni=0;ni<NI;ni++)
        acc[mi][ni] = __builtin_amdgcn_mfma_f32_16x16x32_bf16(af[mi], bfr[ni], acc[mi][ni], 0,0,0);
      __builtin_amdgcn_s_setprio(0);
    }
  };

  int NT = K / BK;
  stage(0, 0);
  __syncthreads();
  int cur = 0;
  for (int t=0; t<NT; ++t){
    if (t+1 < NT) stage(cur^1, (t+1)*BK);
    compute(cur);
    __syncthreads();
    cur ^= 1;
  }

  long cbase = (long)slot*cSlot + (long)h*cHead;
  int rbase = lg*4;
  #pragma unroll
  for (int mi=0;mi<MI;mi++)
  #pragma unroll
  for (int ni=0;ni<NI;ni++){
    f32x4 v = acc[mi][ni];
    int n = bn0 + wn*WTN + ni*16 + lr;
    float bv = bp ? bp[n] : 0.f;
    float scv = (n < scaleNlim) ? scaleVal : 1.f;
    #pragma unroll
    for (int r=0;r<4;r++){
      int m = bm0 + wm*WTM + mi*16 + rbase + r;
      float val = (v[r] + bv) * scv;
      if (relu) val = fmaxf(val, 0.f);
      long o = cbase + (long)m*ldc + n;
      if (f32out) ((float*)Cp)[o] = val;
      else ((unsigned short*)Cp)[o] = f2bf(val);
    }
  }
}

// ---------------- residual add + LayerNorm (per-slot out) ----------------
__global__ void __launch_bounds__(256) add_ln_k(
    const float* __restrict__ Ab, int aDiv, long aStride,
    const float* __restrict__ Bb, long bStride,
    const float* __restrict__ G, const float* __restrict__ Bt,
    const int* __restrict__ eidx,
    float* __restrict__ OutF, unsigned short* __restrict__ OutB)
{
  int row = blockIdx.x*4 + (threadIdx.x>>6);
  int slot = row>>8, t = row&255;
  int lane = threadIdx.x&63;
  const float* a = Ab + (long)(slot/aDiv)*aStride + (long)t*D_;
  const float* b = Bb + (long)slot*bStride + (long)t*D_;
  int e = eidx[slot];
  const float* g  = G  + (long)e*D_;
  const float* bt = Bt + (long)e*D_;
  float x[8]; float s=0.f;
  #pragma unroll
  for (int i=0;i<8;i++){ x[i] = a[lane+i*64]+b[lane+i*64]; s+=x[i]; }
  #pragma unroll
  for (int o=32;o;o>>=1) s += __shfl_xor(s,o);
  float m = s*(1.f/D_);
  float q=0.f;
  #pragma unroll
  for (int i=0;i<8;i++){ float d=x[i]-m; q+=d*d; }
  #pragma unroll
  for (int o=32;o;o>>=1) q += __shfl_xor(q,o);
  float rs = rsqrtf(q*(1.f/D_)+1e-5f);
  long ob = (long)slot*(T_*D_) + (long)t*D_;
  #pragma unroll
  for (int i=0;i<8;i++){
    int d = lane+i*64;
    float y = (x[i]-m)*rs*g[d]+bt[d];
    OutF[ob+d]=y;
    if (OutB) OutB[ob+d]=f2bf(y);
  }
}

// ---------------- residual add + LayerNorm (n3) + weighted slot combine ----------------
__global__ void __launch_bounds__(256) add_ln_comb_k(
    const float* __restrict__ x2, const float* __restrict__ proj,
    const float* __restrict__ G, const float* __restrict__ Bt,
    const int* __restrict__ eidx, const float* __restrict__ wgt,
    float* __restrict__ dstF, unsigned short* __restrict__ dstB)
{
  int row = blockIdx.x*4 + (threadIdx.x>>6);   // 0..B*T-1 : b*256+t
  int b = row>>8, t = row&255;
  int lane = threadIdx.x&63;
  float out[8];
  #pragma unroll
  for (int i=0;i<8;i++) out[i]=0.f;
  #pragma unroll
  for (int s2i=0;s2i<2;s2i++){
    int slot = 2*b + s2i;
    int e = eidx[slot];
    float w = wgt[slot];
    const float* a = x2 + (long)slot*(T_*D_) + (long)t*D_;
    const float* p = proj + (long)slot*(T_*D_) + (long)t*D_;
    const float* g  = G  + (long)e*D_;
    const float* bt = Bt + (long)e*D_;
    float x[8]; float s=0.f;
    #pragma unroll
    for (int i=0;i<8;i++){ x[i] = a[lane+i*64]+p[lane+i*64]; s+=x[i]; }
    #pragma unroll
    for (int o=32;o;o>>=1) s += __shfl_xor(s,o);
    float m = s*(1.f/D_);
    float q=0.f;
    #pragma unroll
    for (int i=0;i<8;i++){ float d=x[i]-m; q+=d*d; }
    #pragma unroll
    for (int o=32;o;o>>=1) q += __shfl_xor(q,o);
    float rs = rsqrtf(q*(1.f/D_)+1e-5f);
    #pragma unroll
    for (int i=0;i<8;i++){
      int d = lane+i*64;
      out[i] += w*((x[i]-m)*rs*g[d]+bt[d]);
    }
  }
  long ob = (long)row*D_;
  #pragma unroll
  for (int i=0;i<8;i++){
    int d = lane+i*64;
    dstF[ob+d] = out[i];
    dstB[ob+d] = f2bf(out[i]);
  }
}

extern "C" void kernel_launch(void* const* d_in, const int* in_sizes, int n_in,
                              void* d_out, int out_size, void* d_ws, size_t ws_size,
                              hipStream_t stream)
{
  const float* tgt      = (const float*)d_in[0];
  const float* memory   = (const float*)d_in[1];
  const float* router_w = (const float*)d_in[2];
  const float* sa_in_w  = (const float*)d_in[3];
  const float* sa_in_b  = (const float*)d_in[4];
  const float* sa_out_w = (const float*)d_in[5];
  const float* sa_out_b = (const float*)d_in[6];
  const float* ca_in_w  = (const float*)d_in[7];
  const float* ca_in_b  = (const float*)d_in[8];
  const float* ca_out_w = (const float*)d_in[9];
  const float* ca_out_b = (const float*)d_in[10];
  const float* lin1_w   = (const float*)d_in[11];
  const float* lin1_b   = (const float*)d_in[12];
  const float* lin2_w   = (const float*)d_in[13];
  const float* lin2_b   = (const float*)d_in[14];
  const float* n1_g = (const float*)d_in[15];
  const float* n1_b = (const float*)d_in[16];
  const float* n2_g = (const float*)d_in[17];
  const float* n2_b = (const float*)d_in[18];
  const float* n3_g = (const float*)d_in[19];
  const float* n3_b = (const float*)d_in[20];

  char* ws = (char*)d_ws;
  size_t off = 0;
  auto alloc = [&](size_t bytes)->char*{
    char* p = ws + off; off += (bytes + 255) & ~(size_t)255; return p;
  };
  unsigned short* xb    = (unsigned short*)alloc(2ull*B_*T_*D_);
  unsigned short* memb  = (unsigned short*)alloc(2ull*B_*S_*D_);
  float*          x     = (float*)alloc(4ull*B_*T_*D_);
  int*            eidx  = (int*)alloc(4ull*NSLOT);
  float*          wgt   = (float*)alloc(4ull*NSLOT);
  unsigned short* wSaIn  = (unsigned short*)alloc(2ull*E_*3*D_*D_);
  unsigned short* wSaOut = (unsigned short*)alloc(2ull*E_*D_*D_);
  unsigned short* wCaIn  = (unsigned short*)alloc(2ull*E_*3*D_*D_);
  unsigned short* wCaOut = (unsigned short*)alloc(2ull*E_*D_*D_);
  unsigned short* wL1    = (unsigned short*)alloc(2ull*E_*DFF_*D_);
  unsigned short* wL2    = (unsigned short*)alloc(2ull*E_*D_*DFF_);
  unsigned short* qkv   = (unsigned short*)alloc(2ull*NSLOT*T_*3*D_);
  unsigned short* ffh   = (unsigned short*)alloc(2ull*NSLOT*T_*DFF_);
  unsigned short* attn  = (unsigned short*)alloc(2ull*NSLOT*T_*D_);
  float*          proj  = (float*)alloc(4ull*NSLOT*T_*D_);
  float*          x1    = (float*)alloc(4ull*NSLOT*T_*D_);
  unsigned short* x1b   = (unsigned short*)alloc(2ull*NSLOT*T_*D_);
  unsigned short* cq    = (unsigned short*)alloc(2ull*NSLOT*T_*D_);
  unsigned short* mkv   = (unsigned short*)alloc(2ull*NSLOT*S_*2*D_);
  float*          x2    = (float*)alloc(4ull*NSLOT*T_*D_);
  unsigned short* x2b   = (unsigned short*)alloc(2ull*NSLOT*T_*D_);
  unsigned short* Vt1   = cq;   // alias: [slot][h][64][T]; cq written after fattn-self consumed Vt1
  unsigned short* Vt2   = qkv;  // alias: [slot][h][64][S]; qkv dead after fattn-self

  cast_bf16_k<<<1024,256,0,stream>>>(tgt,    xb,   (long)B_*T_*D_);
  cast_bf16_k<<<1024,256,0,stream>>>(memory, memb, (long)B_*S_*D_);

  const float* xcur = tgt;
  for (int l=0; l<L_; ++l){
    route_k<<<B_,256,0,stream>>>(xcur, router_w + (size_t)l*E_*D_, eidx, wgt);
    cast_weights_k<<<2048,256,0,stream>>>(
      sa_in_w  + (size_t)l*E_*3*D_*D_, sa_out_w + (size_t)l*E_*D_*D_,
      ca_in_w  + (size_t)l*E_*3*D_*D_, ca_out_w + (size_t)l*E_*D_*D_,
      lin1_w   + (size_t)l*E_*DFF_*D_, lin2_w   + (size_t)l*E_*D_*DFF_,
      wSaIn, wSaOut, wCaIn, wCaOut, wL1, wL2);

    // QKV = x @ sa_in^T + b  (Q cols scaled by 1/8)
    gemm_lds<128,256,64,64,32><<<dim3(6,2,NSLOT),512,0,stream>>>(
      xb, (long)T_*D_, 2, 0, D_,
      wSaIn, 0, 0, (long)3*D_*D_, D_,
      eidx, sa_in_b + (size_t)l*E_*3*D_, 3*D_,
      qkv, (long)T_*3*D_, 0, 3*D_,
      512, 1, 0, 0, D_, 0.125f);
    // Vt1 = transpose of self V
    vtrans_k<<<dim3(T_/64,H_,NSLOT),256,0,stream>>>(
      qkv + 2*D_, (long)T_*3*D_, 3*D_, Vt1, T_);
    // fused self-attention
    fattn_k<4><<<dim3(T_/64, NSLOT*H_),256,0,stream>>>(
      qkv, (long)T_*3*D_, 3*D_,
      qkv + D_, (long)T_*3*D_, 3*D_,
      Vt1, attn, (long)T_*D_, D_);
    // self-attn out proj (fp32 out)
    gemm_lds<128,128,64,32,64><<<dim3(4,2,NSLOT),512,0,stream>>>(
      attn, (long)T_*D_, 1, 0, D_,
      wSaOut, 0, 0, (long)D_*D_, D_,
      eidx, sa_out_b + (size_t)l*E_*D_, D_,
      proj, (long)T_*D_, 0, D_,
      512, 1, 1, 0, 0, 1.f);
    add_ln_k<<<2048,256,0,stream>>>(xcur, 2, (long)T_*D_, proj, (long)T_*D_,
      n1_g + (size_t)l*E_*D_, n1_b + (size_t)l*E_*D_, eidx, x1, x1b);
    // cross-attn Q (scaled)
    gemm_lds<128,128,64,32,64><<<dim3(4,2,NSLOT),512,0,stream>>>(
      x1b, (long)T_*D_, 1, 0, D_,
      wCaIn, 0, 0, (long)3*D_*D_, D_,
      eidx, ca_in_b + (size_t)l*E_*3*D_, 3*D_,
      cq, (long)T_*D_, 0, D_,
      512, 1, 0, 0, D_, 0.125f);
    // cross-attn K,V from memory
    gemm_lds<128,256,64,64,32><<<dim3(4,4,NSLOT),512,0,stream>>>(
      memb, (long)S_*D_, 2, 0, D_,
      wCaIn + (size_t)D_*D_, 0, 0, (long)3*D_*D_, D_,
      eidx, ca_in_b + (size_t)l*E_*3*D_ + D_, 3*D_,
      mkv, (long)S_*2*D_, 0, 2*D_,
      512, 1, 0, 0, 0, 1.f);
    // Vt2 = transpose of cross V
    vtrans_k<<<dim3(S_/64,H_,NSLOT),256,0,stream>>>(
      mkv + D_, (long)S_*2*D_, 2*D_, Vt2, S_);
    // fused cross-attention
    fattn_k<8><<<dim3(T_/64, NSLOT*H_),256,0,stream>>>(
      cq, (long)T_*D_, D_,
      mkv, (long)S_*2*D_, 2*D_,
      Vt2, attn, (long)T_*D_, D_);
    // cross-attn out proj (fp32 out)
    gemm_lds<128,128,64,32,64><<<dim3(4,2,NSLOT),512,0,stream>>>(
      attn, (long)T_*D_, 1, 0, D_,
      wCaOut, 0, 0, (long)D_*D_, D_,
      eidx, ca_out_b + (size_t)l*E_*D_, D_,
      proj, (long)T_*D_, 0, D_,
      512, 1, 1, 0, 0, 1.f);
    add_ln_k<<<2048,256,0,stream>>>(x1, 1, (long)T_*D_, proj, (long)T_*D_,
      n2_g + (size_t)l*E_*D_, n2_b + (size_t)l*E_*D_, eidx, x2, x2b);
    // FFN1 (+relu)
    gemm_lds<128,256,64,64,32><<<dim3(8,2,NSLOT),512,0,stream>>>(
      x2b, (long)T_*D_, 1, 0, D_,
      wL1, 0, 0, (long)DFF_*D_, D_,
      eidx, lin1_b + (size_t)l*E_*DFF_, DFF_,
      ffh, (long)T_*DFF_, 0, DFF_,
      512, 1, 0, 1, 0, 1.f);
    // FFN2 (fp32 out)
    gemm_lds<128,128,64,32,64><<<dim3(4,2,NSLOT),512,0,stream>>>(
      ffh, (long)T_*DFF_, 1, 0, DFF_,
      wL2, 0, 0, (long)D_*DFF_, DFF_,
      eidx, lin2_b + (size_t)l*E_*D_, D_,
      proj, (long)T_*D_, 0, D_,
      2048, 1, 1, 0, 0, 1.f);
    // n3 LN + weighted combine of the two slots (writes next x / xb, or d_out)
    float* dstF = (l==L_-1) ? (float*)d_out : x;
    add_ln_comb_k<<<1024,256,0,stream>>>(x2, proj,
      n3_g + (size_t)l*E_*D_, n3_b + (size_t)l*E_*D_, eidx, wgt, dstF, xb);
    xcur = x;
  }
}

// Round 9
// 1093.040 us; speedup vs baseline: 1.1284x; 1.0435x over previous
//
#include <hip/hip_runtime.h>
#include <hip/hip_bf16.h>

#define L_ 4
#define E_ 4
#define D_ 512
#define DFF_ 2048
#define H_ 8
#define B_ 16
#define T_ 256
#define S_ 512
#define HD_ 64
#define NSLOT 32   // B * K

typedef __attribute__((ext_vector_type(4))) float f32x4;
typedef __attribute__((ext_vector_type(8))) short bf16x8;
typedef __attribute__((ext_vector_type(4))) int i32x4;

static __device__ __forceinline__ float bf2f(unsigned short u){
  union{float f; unsigned u;} c; c.u = ((unsigned)u)<<16; return c.f;
}
static __device__ __forceinline__ unsigned short f2bf(float f){
  union{float f; unsigned u;} c; c.f=f;
  unsigned u=c.u;
  return (unsigned short)((u + 0x7FFFu + ((u>>16)&1u))>>16);
}

static __device__ __forceinline__ void gload16(const unsigned short* g, unsigned short* l){
  __builtin_amdgcn_global_load_lds(
      (const __attribute__((address_space(1))) void*)g,
      (__attribute__((address_space(3))) void*)l, 16, 0, 0);
}

// bijective XCD-chunked block remap (m204): hw id (round-robin over 8 XCDs)
// -> logical id such that each XCD owns a contiguous logical chunk.
static __device__ __forceinline__ int xcd_swz(int orig, int nwg){
  int q = nwg >> 3, r = nwg & 7;
  int xcd = orig & 7, idx = orig >> 3;
  return (xcd < r) ? (xcd*(q+1) + idx) : (r*(q+1) + (xcd-r)*q + idx);
}

// ---------------- routing ----------------
__global__ void __launch_bounds__(256) route_k(const float* __restrict__ x,
    const float* __restrict__ rw, int* __restrict__ eidx, float* __restrict__ wgt)
{
  __shared__ float pooled[D_];
  __shared__ float logit[E_];
  int b = blockIdx.x, tid = threadIdx.x;
  for (int d = tid; d < D_; d += 256) {
    float s = 0.f;
    const float* xp = x + ((long)b*T_)*D_ + d;
    for (int t=0;t<T_;t++) s += xp[(long)t*D_];
    pooled[d] = s * (1.f/T_);
  }
  __syncthreads();
  int wave = tid>>6, lane = tid&63;
  {
    float s=0.f;
    const float* w = rw + (long)wave*D_;
    for (int d=lane; d<D_; d+=64) s += pooled[d]*w[d];
    #pragma unroll
    for (int o=32;o;o>>=1) s += __shfl_xor(s,o);
    if (lane==0) logit[wave] = s;
  }
  __syncthreads();
  if (tid==0){
    int i1=0; float v1=logit[0];
    for (int e=1;e<E_;e++) if (logit[e] > v1){ v1=logit[e]; i1=e; }
    int i2=-1; float v2=-3.4e38f;
    for (int e=0;e<E_;e++) if (e!=i1 && logit[e] > v2){ v2=logit[e]; i2=e; }
    float e2 = __expf(v2 - v1);
    float w1 = 1.f/(1.f+e2);
    eidx[2*b]=i1; eidx[2*b+1]=i2;
    wgt[2*b]=w1; wgt[2*b+1]=e2*w1;
  }
}

// ---------------- casts ----------------
__global__ void __launch_bounds__(256) cast_bf16_k(const float* __restrict__ in,
    unsigned short* __restrict__ out, long n){
  long i = ((long)blockIdx.x*blockDim.x + threadIdx.x)*4;
  long st = (long)gridDim.x*blockDim.x*4;
  for (; i<n; i+=st){
    float4 v = *(const float4*)(in+i);
    ushort4 o; o.x=f2bf(v.x); o.y=f2bf(v.y); o.z=f2bf(v.z); o.w=f2bf(v.w);
    *(ushort4*)(out+i) = o;
  }
}

// fused per-layer weight cast (6 segments)
__global__ void __launch_bounds__(256) cast_weights_k(
    const float* __restrict__ s0, const float* __restrict__ s1,
    const float* __restrict__ s2, const float* __restrict__ s3,
    const float* __restrict__ s4, const float* __restrict__ s5,
    unsigned short* __restrict__ d0, unsigned short* __restrict__ d1,
    unsigned short* __restrict__ d2, unsigned short* __restrict__ d3,
    unsigned short* __restrict__ d4, unsigned short* __restrict__ d5)
{
  const long N0=(long)E_*3*D_*D_, N1=(long)E_*D_*D_;
  const long N2=N0, N3=N1, N4=(long)E_*DFF_*D_, N5=N4;
  const long total = N0+N1+N2+N3+N4+N5;
  long i = ((long)blockIdx.x*256 + threadIdx.x)*4;
  long st = (long)gridDim.x*256*4;
  for (; i<total; i+=st){
    const float* s; unsigned short* d; long j = i;
    if (j < N0){ s=s0; d=d0; }
    else if ((j-=N0) < N1){ s=s1; d=d1; }
    else if ((j-=N1) < N2){ s=s2; d=d2; }
    else if ((j-=N2) < N3){ s=s3; d=d3; }
    else if ((j-=N3) < N4){ s=s4; d=d4; }
    else { j-=N4; s=s5; d=d5; }
    float4 v = *(const float4*)(s+j);
    ushort4 o; o.x=f2bf(v.x); o.y=f2bf(v.y); o.z=f2bf(v.z); o.w=f2bf(v.w);
    *(ushort4*)(d+j) = o;
  }
}

// ---------------- V transpose: [rows, 64-per-head strided] -> [slot][h][64][rows] ----------------
__global__ void __launch_bounds__(256) vtrans_k(const unsigned short* __restrict__ src,
    long sSlot, int ld, unsigned short* __restrict__ dst, int rows)
{
  __shared__ unsigned short t[64][68];
  int s0 = blockIdx.x*64; int h = blockIdx.y; int slot = blockIdx.z;
  const unsigned short* sp = src + (long)slot*sSlot + (long)h*64;
  int c = threadIdx.x&63, w = threadIdx.x>>6;
  #pragma unroll
  for (int i=0;i<16;i++){
    int r = i*4 + w;
    t[r][c] = sp[(long)(s0+r)*ld + c];
  }
  __syncthreads();
  unsigned short* dp = dst + ((long)slot*H_ + h)*((long)64*rows) + s0;
  #pragma unroll
  for (int i=0;i<16;i++){
    int d = i*4 + w;
    dp[(long)d*rows + c] = t[c][d];
  }
}

// ---------------- fused flash attention (async-stage split, setprio, XCD swizzle) ----------------
template<int NT>   // K tiles of 64: 4 (self) or 8 (cross)
__global__ void __launch_bounds__(256) fattn_k(
    const unsigned short* __restrict__ Qg, long qSlot, int ldq,
    const unsigned short* __restrict__ Kg, long kSlot, int ldk,
    const unsigned short* __restrict__ Vtg,
    unsigned short* __restrict__ Og, long oSlot, int ldo)
{
  constexpr int SLEN = NT*64;
  __shared__ unsigned short K_lds[64][72];
  __shared__ unsigned short V_lds[64][72];
  __shared__ unsigned short P_lds[4][16][72];

  // XCD-chunked remap: q-blocks of one (slot,head) become linear-adjacent -> same XCD L2
  int nwg = gridDim.x*gridDim.y;
  int wg = xcd_swz(blockIdx.x + gridDim.x*blockIdx.y, nwg);
  int qb = wg % gridDim.x;
  int z  = wg / gridDim.x;        // slot*H + h
  int slot = z >> 3, h = z & 7;
  int tid = threadIdx.x, wave = tid>>6, lane = tid&63;
  int lr = lane&15, lg = lane>>4;
  int lk = lg*8;

  const unsigned short* Qp = Qg + (long)slot*qSlot + (long)h*HD_;
  const unsigned short* Kp = Kg + (long)slot*kSlot + (long)h*HD_;
  const unsigned short* Vp = Vtg + (long)z*((long)HD_*SLEN);

  bf16x8 qf[2];
  {
    int qrow = qb*64 + wave*16 + lr;
    const unsigned short* qr = Qp + (long)qrow*ldq;
    qf[0] = *(const bf16x8*)(qr + lk);
    qf[1] = *(const bf16x8*)(qr + 32 + lk);
  }

  float m_prev[4], l_run[4];
  f32x4 acc_o[4];
  #pragma unroll
  for (int r=0;r<4;r++){ m_prev[r]=-1e30f; l_run[r]=0.f; }
  #pragma unroll
  for (int ni=0;ni<4;ni++) acc_o[ni]=(f32x4){0.f,0.f,0.f,0.f};

  int srow = tid>>3, sch = tid&7;

  // prologue: load tile 0 into regs
  i32x4 kr0 = *(const i32x4*)(Kp + (long)srow*ldk + sch*8);
  i32x4 kr1 = *(const i32x4*)(Kp + (long)(srow+32)*ldk + sch*8);
  i32x4 vr0 = *(const i32x4*)(Vp + (long)srow*SLEN + sch*8);
  i32x4 vr1 = *(const i32x4*)(Vp + (long)(srow+32)*SLEN + sch*8);

  for (int t=0; t<NT; ++t){
    __syncthreads();   // all waves done reading prev tile's LDS
    *(i32x4*)&K_lds[srow][sch*8] = kr0;
    *(i32x4*)&K_lds[srow+32][sch*8] = kr1;
    *(i32x4*)&V_lds[srow][sch*8] = vr0;
    *(i32x4*)&V_lds[srow+32][sch*8] = vr1;
    __syncthreads();

    // issue next tile's loads NOW; they complete under the compute below
    int tn = (t+1 < NT) ? t+1 : t;
    int k0n = tn*64;
    kr0 = *(const i32x4*)(Kp + (long)(k0n+srow)*ldk + sch*8);
    kr1 = *(const i32x4*)(Kp + (long)(k0n+srow+32)*ldk + sch*8);
    vr0 = *(const i32x4*)(Vp + (long)srow*SLEN + k0n + sch*8);
    vr1 = *(const i32x4*)(Vp + (long)(srow+32)*SLEN + k0n + sch*8);

    // S = Q @ K^T
    f32x4 s[4];
    #pragma unroll
    for (int ni=0;ni<4;ni++) s[ni]=(f32x4){0.f,0.f,0.f,0.f};
    __builtin_amdgcn_s_setprio(1);
    #pragma unroll
    for (int ki=0;ki<2;ki++){
      #pragma unroll
      for (int ni=0;ni<4;ni++){
        bf16x8 kf = *(const bf16x8*)&K_lds[ni*16+lr][ki*32+lk];
        s[ni] = __builtin_amdgcn_mfma_f32_16x16x32_bf16(qf[ki], kf, s[ni],0,0,0);
      }
    }
    __builtin_amdgcn_s_setprio(0);
    // online softmax
    float tmax[4], corr[4], mnew[4];
    #pragma unroll
    for (int r=0;r<4;r++){
      tmax[r] = fmaxf(fmaxf(s[0][r],s[1][r]),fmaxf(s[2][r],s[3][r]));
      #pragma unroll
      for (int msk=1; msk<16; msk<<=1) tmax[r]=fmaxf(tmax[r], __shfl_xor(tmax[r],msk));
      mnew[r] = fmaxf(m_prev[r], tmax[r]);
      corr[r] = __expf(m_prev[r]-mnew[r]);
      m_prev[r] = mnew[r];
    }
    float rs[4] = {0.f,0.f,0.f,0.f};
    #pragma unroll
    for (int ni=0;ni<4;ni++){
      #pragma unroll
      for (int r=0;r<4;r++){
        float p = __expf(s[ni][r]-mnew[r]);
        rs[r] += p;
        P_lds[wave][lg*4+r][ni*16+lr] = f2bf(p);
      }
    }
    #pragma unroll
    for (int r=0;r<4;r++){
      #pragma unroll
      for (int msk=1; msk<16; msk<<=1) rs[r] += __shfl_xor(rs[r],msk);
      l_run[r] = l_run[r]*corr[r] + rs[r];
      #pragma unroll
      for (int ni=0;ni<4;ni++) acc_o[ni][r] *= corr[r];
    }
    // O += P @ V   (P_lds is wave-private: no barrier needed, lgkmcnt suffices)
    __builtin_amdgcn_s_setprio(1);
    #pragma unroll
    for (int ki=0;ki<2;ki++){
      bf16x8 pf = *(const bf16x8*)&P_lds[wave][lr][ki*32+lk];
      #pragma unroll
      for (int ni=0;ni<4;ni++){
        bf16x8 vf = *(const bf16x8*)&V_lds[ni*16+lr][ki*32+lk];
        acc_o[ni] = __builtin_amdgcn_mfma_f32_16x16x32_bf16(pf, vf, acc_o[ni],0,0,0);
      }
    }
    __builtin_amdgcn_s_setprio(0);
  }
  unsigned short* Op = Og + (long)slot*oSlot + (long)h*HD_;
  #pragma unroll
  for (int r=0;r<4;r++){
    float inv = 1.f/l_run[r];
    int q = qb*64 + wave*16 + lg*4 + r;
    #pragma unroll
    for (int ni=0;ni<4;ni++)
      Op[(long)q*ldo + ni*16 + lr] = f2bf(acc_o[ni][r]*inv);
  }
}

// ---------------- LDS-staged GEMM  C = A @ W^T (+bias)(*scale)(relu) ----------------
// dbuf LDS, chunk-XOR swizzle, 8 waves (512 thr), XCD-chunked block remap.
//   <128,128,64,32,64> : small GEMMs (64KB LDS, 2 blocks/CU)
//   <128,256,64,64,32> : big GEMMs (49KB LDS, ~3 blocks/CU, 64x64 wave tile)
template<int BM, int BN, int WTM, int WTN, int BK>
__global__ void __launch_bounds__(512) gemm_lds(
    const unsigned short* __restrict__ A, long aSlot, int aDiv, long aHead, int lda,
    const unsigned short* __restrict__ W, long wSlot, long wHead, long wExp, int ldw,
    const int* __restrict__ eidx, const float* __restrict__ bias, long biasExp,
    void* __restrict__ Cp, long cSlot, long cHead, int ldc,
    int K, int HZ, int f32out, int relu, int scaleNlim, float scaleVal)
{
  constexpr int WAVES_N = BN/WTN;
  constexpr int MI = WTM/16, NI = WTN/16;
  constexpr int SLOTS = BK/8;            // 16B chunks per row
  static_assert((BM/WTM)*(BN/WTN) == 8, "8 waves");
  static_assert((BM*SLOTS)%512==0 && (BN*SLOTS)%512==0, "stage coverage");
  __shared__ unsigned short smem[2*(BM+BN)*BK];

  // XCD-chunked remap: all (x,y) blocks of a slot become linear-adjacent -> same XCD L2,
  // so A-panels and same-expert weight panels are fetched once per XCD.
  int nwg = gridDim.x*gridDim.y*gridDim.z;
  int wg = xcd_swz(blockIdx.x + gridDim.x*(blockIdx.y + gridDim.y*blockIdx.z), nwg);
  int bx = wg % gridDim.x; int t1 = wg / gridDim.x;
  int by = t1 % gridDim.y; int z  = t1 / gridDim.y;

  int slot = z / HZ;
  int h = z - slot*HZ;
  int e = eidx ? eidx[slot] : 0;
  const unsigned short* Ap = A + (long)(slot/aDiv)*aSlot + (long)h*aHead;
  const unsigned short* Wp = W + (long)slot*wSlot + (long)h*wHead + (long)e*wExp;
  const float* bp = bias ? (bias + (long)e*biasExp) : nullptr;

  int tid  = threadIdx.x;
  int wave = tid>>6, lane = tid&63;
  int wm = wave / WAVES_N, wn = wave % WAVES_N;
  int bm0 = by*BM;
  int bn0 = bx*BN;
  int lr = lane&15;
  int lg = lane>>4;
  // fragment k-slot swizzle term (uniform across fragments: frag row = base16 + lr)
  int swz = (BK==64) ? (lr&7) : ((lr>>1)&3);

  Ap += (long)bm0*lda;
  Wp += (long)bn0*ldw;

  f32x4 acc[MI][NI];
  #pragma unroll
  for (int i=0;i<MI;i++)
  #pragma unroll
  for (int j=0;j<NI;j++) acc[i][j] = (f32x4){0.f,0.f,0.f,0.f};

  // staging: chunk -> LDS linear; global src chunk index is XOR-permuted per row
  auto stage = [&](int buf, int k0){
    unsigned short* as = &smem[(size_t)buf*(BM+BN)*BK];
    unsigned short* bs = as + BM*BK;
    #pragma unroll
    for (int i=0;i<BM*SLOTS/512;i++){
      int cch = i*512 + tid;
      int row = cch / SLOTS, c = cch % SLOTS;
      int cs = (BK==64) ? (c ^ (row&7)) : (c ^ ((row>>1)&3));
      gload16(Ap + (long)row*lda + k0 + (cs<<3), as + cch*8);
    }
    #pragma unroll
    for (int i=0;i<BN*SLOTS/512;i++){
      int cch = i*512 + tid;
      int row = cch / SLOTS, c = cch % SLOTS;
      int cs = (BK==64) ? (c ^ (row&7)) : (c ^ ((row>>1)&3));
      gload16(Wp + (long)row*ldw + k0 + (cs<<3), bs + cch*8);
    }
  };

  auto compute = [&](int buf){
    unsigned short* as = &smem[(size_t)buf*(BM+BN)*BK];
    unsigned short* bs = as + BM*BK;
    #pragma unroll
    for (int ki=0;ki<BK/32;ki++){
      bf16x8 af[MI], bfr[NI];
      #pragma unroll
      for (int mi=0;mi<MI;mi++){
        int row = wm*WTM + mi*16 + lr;
        af[mi] = *(const bf16x8*)&as[row*BK + (((ki*4+lg) ^ swz)<<3)];
      }
      #pragma unroll
      for (int ni=0;ni<NI;ni++){
        int row = wn*WTN + ni*16 + lr;
        bfr[ni] = *(const bf16x8*)&bs[row*BK + (((ki*4+lg) ^ swz)<<3)];
      }
      __builtin_amdgcn_s_setprio(1);
      #pragma unroll
      for (int mi=0;mi<MI;mi++)
      #pragma unroll
      for (int ni=0;ni<NI;ni++)
        acc[mi][ni] = __builtin_amdgcn_mfma_f32_16x16x32_bf16(af[mi], bfr[ni], acc[mi][ni], 0,0,0);
      __builtin_amdgcn_s_setprio(0);
    }
  };

  int NT = K / BK;
  stage(0, 0);
  __syncthreads();
  int cur = 0;
  for (int t=0; t<NT; ++t){
    if (t+1 < NT) stage(cur^1, (t+1)*BK);
    compute(cur);
    __syncthreads();
    cur ^= 1;
  }

  long cbase = (long)slot*cSlot + (long)h*cHead;
  int rbase = lg*4;
  #pragma unroll
  for (int mi=0;mi<MI;mi++)
  #pragma unroll
  for (int ni=0;ni<NI;ni++){
    f32x4 v = acc[mi][ni];
    int n = bn0 + wn*WTN + ni*16 + lr;
    float bv = bp ? bp[n] : 0.f;
    float scv = (n < scaleNlim) ? scaleVal : 1.f;
    #pragma unroll
    for (int r=0;r<4;r++){
      int m = bm0 + wm*WTM + mi*16 + rbase + r;
      float val = (v[r] + bv) * scv;
      if (relu) val = fmaxf(val, 0.f);
      long o = cbase + (long)m*ldc + n;
      if (f32out) ((float*)Cp)[o] = val;
      else ((unsigned short*)Cp)[o] = f2bf(val);
    }
  }
}

// ---------------- residual add + LayerNorm (per-slot out) ----------------
__global__ void __launch_bounds__(256) add_ln_k(
    const float* __restrict__ Ab, int aDiv, long aStride,
    const float* __restrict__ Bb, long bStride,
    const float* __restrict__ G, const float* __restrict__ Bt,
    const int* __restrict__ eidx,
    float* __restrict__ OutF, unsigned short* __restrict__ OutB)
{
  int row = blockIdx.x*4 + (threadIdx.x>>6);
  int slot = row>>8, t = row&255;
  int lane = threadIdx.x&63;
  const float* a = Ab + (long)(slot/aDiv)*aStride + (long)t*D_;
  const float* b = Bb + (long)slot*bStride + (long)t*D_;
  int e = eidx[slot];
  const float* g  = G  + (long)e*D_;
  const float* bt = Bt + (long)e*D_;
  float x[8]; float s=0.f;
  #pragma unroll
  for (int i=0;i<8;i++){ x[i] = a[lane+i*64]+b[lane+i*64]; s+=x[i]; }
  #pragma unroll
  for (int o=32;o;o>>=1) s += __shfl_xor(s,o);
  float m = s*(1.f/D_);
  float q=0.f;
  #pragma unroll
  for (int i=0;i<8;i++){ float d=x[i]-m; q+=d*d; }
  #pragma unroll
  for (int o=32;o;o>>=1) q += __shfl_xor(q,o);
  float rs = rsqrtf(q*(1.f/D_)+1e-5f);
  long ob = (long)slot*(T_*D_) + (long)t*D_;
  #pragma unroll
  for (int i=0;i<8;i++){
    int d = lane+i*64;
    float y = (x[i]-m)*rs*g[d]+bt[d];
    OutF[ob+d]=y;
    if (OutB) OutB[ob+d]=f2bf(y);
  }
}

// ---------------- residual add + LayerNorm (n3) + weighted slot combine ----------------
__global__ void __launch_bounds__(256) add_ln_comb_k(
    const float* __restrict__ x2, const float* __restrict__ proj,
    const float* __restrict__ G, const float* __restrict__ Bt,
    const int* __restrict__ eidx, const float* __restrict__ wgt,
    float* __restrict__ dstF, unsigned short* __restrict__ dstB)
{
  int row = blockIdx.x*4 + (threadIdx.x>>6);   // 0..B*T-1 : b*256+t
  int b = row>>8, t = row&255;
  int lane = threadIdx.x&63;
  float out[8];
  #pragma unroll
  for (int i=0;i<8;i++) out[i]=0.f;
  #pragma unroll
  for (int s2i=0;s2i<2;s2i++){
    int slot = 2*b + s2i;
    int e = eidx[slot];
    float w = wgt[slot];
    const float* a = x2 + (long)slot*(T_*D_) + (long)t*D_;
    const float* p = proj + (long)slot*(T_*D_) + (long)t*D_;
    const float* g  = G  + (long)e*D_;
    const float* bt = Bt + (long)e*D_;
    float x[8]; float s=0.f;
    #pragma unroll
    for (int i=0;i<8;i++){ x[i] = a[lane+i*64]+p[lane+i*64]; s+=x[i]; }
    #pragma unroll
    for (int o=32;o;o>>=1) s += __shfl_xor(s,o);
    float m = s*(1.f/D_);
    float q=0.f;
    #pragma unroll
    for (int i=0;i<8;i++){ float d=x[i]-m; q+=d*d; }
    #pragma unroll
    for (int o=32;o;o>>=1) q += __shfl_xor(q,o);
    float rs = rsqrtf(q*(1.f/D_)+1e-5f);
    #pragma unroll
    for (int i=0;i<8;i++){
      int d = lane+i*64;
      out[i] += w*((x[i]-m)*rs*g[d]+bt[d]);
    }
  }
  long ob = (long)row*D_;
  #pragma unroll
  for (int i=0;i<8;i++){
    int d = lane+i*64;
    dstF[ob+d] = out[i];
    dstB[ob+d] = f2bf(out[i]);
  }
}

extern "C" void kernel_launch(void* const* d_in, const int* in_sizes, int n_in,
                              void* d_out, int out_size, void* d_ws, size_t ws_size,
                              hipStream_t stream)
{
  const float* tgt      = (const float*)d_in[0];
  const float* memory   = (const float*)d_in[1];
  const float* router_w = (const float*)d_in[2];
  const float* sa_in_w  = (const float*)d_in[3];
  const float* sa_in_b  = (const float*)d_in[4];
  const float* sa_out_w = (const float*)d_in[5];
  const float* sa_out_b = (const float*)d_in[6];
  const float* ca_in_w  = (const float*)d_in[7];
  const float* ca_in_b  = (const float*)d_in[8];
  const float* ca_out_w = (const float*)d_in[9];
  const float* ca_out_b = (const float*)d_in[10];
  const float* lin1_w   = (const float*)d_in[11];
  const float* lin1_b   = (const float*)d_in[12];
  const float* lin2_w   = (const float*)d_in[13];
  const float* lin2_b   = (const float*)d_in[14];
  const float* n1_g = (const float*)d_in[15];
  const float* n1_b = (const float*)d_in[16];
  const float* n2_g = (const float*)d_in[17];
  const float* n2_b = (const float*)d_in[18];
  const float* n3_g = (const float*)d_in[19];
  const float* n3_b = (const float*)d_in[20];

  char* ws = (char*)d_ws;
  size_t off = 0;
  auto alloc = [&](size_t bytes)->char*{
    char* p = ws + off; off += (bytes + 255) & ~(size_t)255; return p;
  };
  unsigned short* xb    = (unsigned short*)alloc(2ull*B_*T_*D_);
  unsigned short* memb  = (unsigned short*)alloc(2ull*B_*S_*D_);
  float*          x     = (float*)alloc(4ull*B_*T_*D_);
  int*            eidx  = (int*)alloc(4ull*NSLOT);
  float*          wgt   = (float*)alloc(4ull*NSLOT);
  unsigned short* wSaIn  = (unsigned short*)alloc(2ull*E_*3*D_*D_);
  unsigned short* wSaOut = (unsigned short*)alloc(2ull*E_*D_*D_);
  unsigned short* wCaIn  = (unsigned short*)alloc(2ull*E_*3*D_*D_);
  unsigned short* wCaOut = (unsigned short*)alloc(2ull*E_*D_*D_);
  unsigned short* wL1    = (unsigned short*)alloc(2ull*E_*DFF_*D_);
  unsigned short* wL2    = (unsigned short*)alloc(2ull*E_*D_*DFF_);
  unsigned short* qkv   = (unsigned short*)alloc(2ull*NSLOT*T_*3*D_);
  unsigned short* ffh   = (unsigned short*)alloc(2ull*NSLOT*T_*DFF_);
  unsigned short* attn  = (unsigned short*)alloc(2ull*NSLOT*T_*D_);
  float*          proj  = (float*)alloc(4ull*NSLOT*T_*D_);
  float*          x1    = (float*)alloc(4ull*NSLOT*T_*D_);
  unsigned short* x1b   = (unsigned short*)alloc(2ull*NSLOT*T_*D_);
  unsigned short* cq    = (unsigned short*)alloc(2ull*NSLOT*T_*D_);
  unsigned short* mkv   = (unsigned short*)alloc(2ull*NSLOT*S_*2*D_);
  float*          x2    = (float*)alloc(4ull*NSLOT*T_*D_);
  unsigned short* x2b   = (unsigned short*)alloc(2ull*NSLOT*T_*D_);
  unsigned short* Vt1   = cq;   // alias: [slot][h][64][T]; cq written after fattn-self consumed Vt1
  unsigned short* Vt2   = qkv;  // alias: [slot][h][64][S]; qkv dead after fattn-self

  cast_bf16_k<<<1024,256,0,stream>>>(tgt,    xb,   (long)B_*T_*D_);
  cast_bf16_k<<<1024,256,0,stream>>>(memory, memb, (long)B_*S_*D_);

  const float* xcur = tgt;
  for (int l=0; l<L_; ++l){
    route_k<<<B_,256,0,stream>>>(xcur, router_w + (size_t)l*E_*D_, eidx, wgt);
    cast_weights_k<<<2048,256,0,stream>>>(
      sa_in_w  + (size_t)l*E_*3*D_*D_, sa_out_w + (size_t)l*E_*D_*D_,
      ca_in_w  + (size_t)l*E_*3*D_*D_, ca_out_w + (size_t)l*E_*D_*D_,
      lin1_w   + (size_t)l*E_*DFF_*D_, lin2_w   + (size_t)l*E_*D_*DFF_,
      wSaIn, wSaOut, wCaIn, wCaOut, wL1, wL2);

    // QKV = x @ sa_in^T + b  (Q cols scaled by 1/8)
    gemm_lds<128,256,64,64,32><<<dim3(6,2,NSLOT),512,0,stream>>>(
      xb, (long)T_*D_, 2, 0, D_,
      wSaIn, 0, 0, (long)3*D_*D_, D_,
      eidx, sa_in_b + (size_t)l*E_*3*D_, 3*D_,
      qkv, (long)T_*3*D_, 0, 3*D_,
      512, 1, 0, 0, D_, 0.125f);
    // Vt1 = transpose of self V
    vtrans_k<<<dim3(T_/64,H_,NSLOT),256,0,stream>>>(
      qkv + 2*D_, (long)T_*3*D_, 3*D_, Vt1, T_);
    // fused self-attention
    fattn_k<4><<<dim3(T_/64, NSLOT*H_),256,0,stream>>>(
      qkv, (long)T_*3*D_, 3*D_,
      qkv + D_, (long)T_*3*D_, 3*D_,
      Vt1, attn, (long)T_*D_, D_);
    // self-attn out proj (fp32 out)
    gemm_lds<128,128,64,32,64><<<dim3(4,2,NSLOT),512,0,stream>>>(
      attn, (long)T_*D_, 1, 0, D_,
      wSaOut, 0, 0, (long)D_*D_, D_,
      eidx, sa_out_b + (size_t)l*E_*D_, D_,
      proj, (long)T_*D_, 0, D_,
      512, 1, 1, 0, 0, 1.f);
    add_ln_k<<<2048,256,0,stream>>>(xcur, 2, (long)T_*D_, proj, (long)T_*D_,
      n1_g + (size_t)l*E_*D_, n1_b + (size_t)l*E_*D_, eidx, x1, x1b);
    // cross-attn Q (scaled)
    gemm_lds<128,128,64,32,64><<<dim3(4,2,NSLOT),512,0,stream>>>(
      x1b, (long)T_*D_, 1, 0, D_,
      wCaIn, 0, 0, (long)3*D_*D_, D_,
      eidx, ca_in_b + (size_t)l*E_*3*D_, 3*D_,
      cq, (long)T_*D_, 0, D_,
      512, 1, 0, 0, D_, 0.125f);
    // cross-attn K,V from memory
    gemm_lds<128,256,64,64,32><<<dim3(4,4,NSLOT),512,0,stream>>>(
      memb, (long)S_*D_, 2, 0, D_,
      wCaIn + (size_t)D_*D_, 0, 0, (long)3*D_*D_, D_,
      eidx, ca_in_b + (size_t)l*E_*3*D_ + D_, 3*D_,
      mkv, (long)S_*2*D_, 0, 2*D_,
      512, 1, 0, 0, 0, 1.f);
    // Vt2 = transpose of cross V
    vtrans_k<<<dim3(S_/64,H_,NSLOT),256,0,stream>>>(
      mkv + D_, (long)S_*2*D_, 2*D_, Vt2, S_);
    // fused cross-attention
    fattn_k<8><<<dim3(T_/64, NSLOT*H_),256,0,stream>>>(
      cq, (long)T_*D_, D_,
      mkv, (long)S_*2*D_, 2*D_,
      Vt2, attn, (long)T_*D_, D_);
    // cross-attn out proj (fp32 out)
    gemm_lds<128,128,64,32,64><<<dim3(4,2,NSLOT),512,0,stream>>>(
      attn, (long)T_*D_, 1, 0, D_,
      wCaOut, 0, 0, (long)D_*D_, D_,
      eidx, ca_out_b + (size_t)l*E_*D_, D_,
      proj, (long)T_*D_, 0, D_,
      512, 1, 1, 0, 0, 1.f);
    add_ln_k<<<2048,256,0,stream>>>(x1, 1, (long)T_*D_, proj, (long)T_*D_,
      n2_g + (size_t)l*E_*D_, n2_b + (size_t)l*E_*D_, eidx, x2, x2b);
    // FFN1 (+relu)
    gemm_lds<128,256,64,64,32><<<dim3(8,2,NSLOT),512,0,stream>>>(
      x2b, (long)T_*D_, 1, 0, D_,
      wL1, 0, 0, (long)DFF_*D_, D_,
      eidx, lin1_b + (size_t)l*E_*DFF_, DFF_,
      ffh, (long)T_*DFF_, 0, DFF_,
      512, 1, 0, 1, 0, 1.f);
    // FFN2 (fp32 out)
    gemm_lds<128,128,64,32,64><<<dim3(4,2,NSLOT),512,0,stream>>>(
      ffh, (long)T_*DFF_, 1, 0, DFF_,
      wL2, 0, 0, (long)D_*DFF_, DFF_,
      eidx, lin2_b + (size_t)l*E_*D_, D_,
      proj, (long)T_*D_, 0, D_,
      2048, 1, 1, 0, 0, 1.f);
    // n3 LN + weighted combine of the two slots (writes next x / xb, or d_out)
    float* dstF = (l==L_-1) ? (float*)d_out : x;
    add_ln_comb_k<<<1024,256,0,stream>>>(x2, proj,
      n3_g + (size_t)l*E_*D_, n3_b + (size_t)l*E_*D_, eidx, wgt, dstF, xb);
    xcur = x;
  }
}